// Round 1
// baseline (314.483 us; speedup 1.0000x reference)
//
#include <hip/hip_runtime.h>
#include <cmath>

namespace {

constexpr int HID  = 128;
constexpr int QP   = 1024;   // Q*P
constexpr int N    = 64;
constexpr int NPTS = 4096;   // N*N
constexpr int PAD  = 68;     // row stride (floats) for row-major LDS tiles
constexpr int B    = 16;
constexpr int P    = 32;
constexpr int Q    = 32;

__device__ __forceinline__ float gelu_tanh(float x) {
    const float c0 = 0.7978845608028654f;   // sqrt(2/pi)
    const float c1 = 0.044715f;
    float inner = c0 * (x + c1 * x * x * x);
    return 0.5f * x * (1.0f + tanhf(inner));
}

// ---------------------------------------------------------------------------
// Kernel 1: evaluate the per-dimension MLP kernels on the 64x64 point grid.
// grid (512, 2): blockIdx.y selects dimension; each block handles 8 points
// (same row i, 8 consecutive j). 256 threads.
// Output layout: K[(a*P+c)*4096 + i*64 + j]  (= mlp_out channel o at point).
// ---------------------------------------------------------------------------
__global__ __launch_bounds__(256)
void mlp_kernel(const float* __restrict__ xs1, const float* __restrict__ xs2,
                const float* __restrict__ W0a, const float* __restrict__ b0a,
                const float* __restrict__ W1a, const float* __restrict__ b1a,
                const float* __restrict__ W2a, const float* __restrict__ b2a,
                const float* __restrict__ W0b, const float* __restrict__ b0b,
                const float* __restrict__ W1b, const float* __restrict__ b1b,
                const float* __restrict__ W2b, const float* __restrict__ b2b,
                float* __restrict__ K1out, float* __restrict__ K2out)
{
    const int dim = blockIdx.y;
    const float* xs = dim ? xs2 : xs1;
    const float* W0 = dim ? W0b : W0a;
    const float* b0 = dim ? b0b : b0a;
    const float* W1 = dim ? W1b : W1a;
    const float* b1 = dim ? b1b : b1a;
    const float* W2 = dim ? W2b : W2a;
    const float* b2 = dim ? b2b : b2a;
    float* Kout = dim ? K2out : K1out;

    __shared__ float h0s[8][HID];
    __shared__ float h1s[8][HID];

    const int t    = threadIdx.x;
    const int ch   = t & (HID - 1);
    const int half = t >> 7;              // 0 or 1
    const int p0   = blockIdx.x * 8;      // first point of this block
    const int i    = p0 >> 6;             // row index (same for all 8 points)
    const int j0   = p0 & 63;
    const float y  = xs[i];

    // layer 0: 2 -> 128 (two points per pass)
    #pragma unroll
    for (int pass = 0; pass < 4; ++pass) {
        const int pp = pass * 2 + half;
        const float x = xs[j0 + pp];
        float v = fmaf(y, W0[ch], fmaf(x, W0[HID + ch], b0[ch]));
        h0s[pp][ch] = gelu_tanh(v);
    }
    __syncthreads();

    // layer 1: 128 -> 128 (each half of the block does 4 points)
    {
        const int pp0 = half * 4;
        const float bb = b1[ch];
        float a0 = bb, a1 = bb, a2 = bb, a3 = bb;
        for (int k = 0; k < HID; ++k) {
            const float w = W1[k * HID + ch];
            a0 = fmaf(h0s[pp0 + 0][k], w, a0);
            a1 = fmaf(h0s[pp0 + 1][k], w, a1);
            a2 = fmaf(h0s[pp0 + 2][k], w, a2);
            a3 = fmaf(h0s[pp0 + 3][k], w, a3);
        }
        h1s[pp0 + 0][ch] = gelu_tanh(a0);
        h1s[pp0 + 1][ch] = gelu_tanh(a1);
        h1s[pp0 + 2][ch] = gelu_tanh(a2);
        h1s[pp0 + 3][ch] = gelu_tanh(a3);
    }
    __syncthreads();

    // layer 2: 128 -> 1024, all 8 points per thread-channel
    #pragma unroll
    for (int ob = 0; ob < 4; ++ob) {
        const int o = ob * 256 + t;
        const float bb = b2[o];
        float acc[8];
        #pragma unroll
        for (int pp = 0; pp < 8; ++pp) acc[pp] = bb;
        for (int k = 0; k < HID; ++k) {
            const float w = W2[k * QP + o];
            #pragma unroll
            for (int pp = 0; pp < 8; ++pp)
                acc[pp] = fmaf(h1s[pp][k], w, acc[pp]);
        }
        float* dst = Kout + (size_t)o * NPTS + p0;
        *reinterpret_cast<float4*>(dst)     = make_float4(acc[0], acc[1], acc[2], acc[3]);
        *reinterpret_cast<float4*>(dst + 4) = make_float4(acc[4], acc[5], acc[6], acc[7]);
    }
}

// XOR swizzle for the K2 LDS tile: element (k, m) stored at
// k*64 + ((m/4 ^ (k/4 & 15)) * 4) + m%4.  Makes the mm2 "16 rows, same
// column chunk" read pattern conflict-free.
__device__ __forceinline__ int c_swz(int k, int m) {
    return k * N + ((((m >> 2) ^ ((k >> 2) & 15)) << 2) | (m & 3));
}

// ---------------------------------------------------------------------------
// Kernel 2: out[b,a] = sum_c K1[a,c] @ vw[b,c] @ K2[a,c]^T
// grid 512 = (b,a), 256 threads, 4x4 register tiles.
// ---------------------------------------------------------------------------
__global__ __launch_bounds__(256, 2)
void contract_kernel(const float* __restrict__ u,
                     const float* __restrict__ w1,
                     const float* __restrict__ w2,
                     const float* __restrict__ K1,
                     const float* __restrict__ K2,
                     float* __restrict__ out)
{
    __shared__ float bufA[N * PAD];  // K1 tile, then reused for T
    __shared__ float bufB[N * PAD];  // vw tile
    __shared__ float bufC[N * N];    // K2 tile (swizzled)

    const int b  = blockIdx.x >> 5;
    const int a  = blockIdx.x & 31;
    const int t  = threadIdx.x;
    const int i0 = (t >> 4) * 4;   // output row group
    const int m0 = (t & 15) * 4;   // output col group (also m-group in mm1)

    float acc[4][4];
    #pragma unroll
    for (int r = 0; r < 4; ++r)
        #pragma unroll
        for (int s = 0; s < 4; ++s) acc[r][s] = 0.f;

    for (int c = 0; c < P; ++c) {
        const float* K1p = K1 + (size_t)(a * P + c) * NPTS;
        const float* K2p = K2 + (size_t)(a * P + c) * NPTS;
        const float* up  = u  + (size_t)(b * P + c) * NPTS;

        // ---- stage K1, K2, vw tiles into LDS (coalesced float4) ----
        #pragma unroll
        for (int pass = 0; pass < 4; ++pass) {
            const int g   = (pass * 256 + t) * 4;   // flat float index
            const int r   = g >> 6;                 // row
            const int col = g & 63;                 // col (multiple of 4)
            const float4 k1v = *reinterpret_cast<const float4*>(K1p + g);
            const float4 k2v = *reinterpret_cast<const float4*>(K2p + g);
            const float4 uv  = *reinterpret_cast<const float4*>(up  + g);
            const float4 w2v = *reinterpret_cast<const float4*>(w2 + col);
            const float  w1v = w1[r];
            float4 vwv;
            vwv.x = uv.x * w1v * w2v.x;
            vwv.y = uv.y * w1v * w2v.y;
            vwv.z = uv.z * w1v * w2v.z;
            vwv.w = uv.w * w1v * w2v.w;
            *reinterpret_cast<float4*>(&bufA[r * PAD + col]) = k1v;
            *reinterpret_cast<float4*>(&bufB[r * PAD + col]) = vwv;
            *reinterpret_cast<float4*>(&bufC[c_swz(r, col)]) = k2v;
        }
        __syncthreads();

        // ---- mm1: T[i][m] = sum_j K1[i][j] * vw[j][m] ----
        float tr[4][4];
        #pragma unroll
        for (int r = 0; r < 4; ++r)
            #pragma unroll
            for (int s = 0; s < 4; ++s) tr[r][s] = 0.f;

        #pragma unroll
        for (int jb = 0; jb < 16; ++jb) {
            float4 av[4], bv[4];
            #pragma unroll
            for (int r = 0; r < 4; ++r)
                av[r] = *reinterpret_cast<const float4*>(&bufA[(i0 + r) * PAD + jb * 4]);
            #pragma unroll
            for (int jj = 0; jj < 4; ++jj)
                bv[jj] = *reinterpret_cast<const float4*>(&bufB[(jb * 4 + jj) * PAD + m0]);
            #pragma unroll
            for (int r = 0; r < 4; ++r) {
                tr[r][0] = fmaf(av[r].x, bv[0].x, fmaf(av[r].y, bv[1].x, fmaf(av[r].z, bv[2].x, fmaf(av[r].w, bv[3].x, tr[r][0]))));
                tr[r][1] = fmaf(av[r].x, bv[0].y, fmaf(av[r].y, bv[1].y, fmaf(av[r].z, bv[2].y, fmaf(av[r].w, bv[3].y, tr[r][1]))));
                tr[r][2] = fmaf(av[r].x, bv[0].z, fmaf(av[r].y, bv[1].z, fmaf(av[r].z, bv[2].z, fmaf(av[r].w, bv[3].z, tr[r][2]))));
                tr[r][3] = fmaf(av[r].x, bv[0].w, fmaf(av[r].y, bv[1].w, fmaf(av[r].z, bv[2].w, fmaf(av[r].w, bv[3].w, tr[r][3]))));
            }
        }
        __syncthreads();

        // ---- write T into bufA (K1 tile is dead now) ----
        #pragma unroll
        for (int r = 0; r < 4; ++r)
            *reinterpret_cast<float4*>(&bufA[(i0 + r) * PAD + m0]) =
                make_float4(tr[r][0], tr[r][1], tr[r][2], tr[r][3]);
        __syncthreads();

        // ---- mm2: out[i][k] += sum_m T[i][m] * K2[k][m] ----
        // thread tile: rows i0..i0+3, cols k0..k0+3 (k0 == m0)
        #pragma unroll
        for (int mb = 0; mb < 16; ++mb) {
            float4 tv[4], kv[4];
            #pragma unroll
            for (int r = 0; r < 4; ++r)
                tv[r] = *reinterpret_cast<const float4*>(&bufA[(i0 + r) * PAD + mb * 4]);
            #pragma unroll
            for (int s = 0; s < 4; ++s)
                kv[s] = *reinterpret_cast<const float4*>(&bufC[c_swz(m0 + s, mb * 4)]);
            #pragma unroll
            for (int r = 0; r < 4; ++r)
                #pragma unroll
                for (int s = 0; s < 4; ++s)
                    acc[r][s] = fmaf(tv[r].x, kv[s].x, fmaf(tv[r].y, kv[s].y, fmaf(tv[r].z, kv[s].z, fmaf(tv[r].w, kv[s].w, acc[r][s]))));
        }
        __syncthreads();
    }

    // ---- write output: out[b, a*4096 + i*64 + k] ----
    float* op = out + (size_t)b * (Q * NPTS) + (size_t)a * NPTS;
    #pragma unroll
    for (int r = 0; r < 4; ++r)
        *reinterpret_cast<float4*>(op + (i0 + r) * N + m0) =
            make_float4(acc[r][0], acc[r][1], acc[r][2], acc[r][3]);
}

} // namespace

extern "C" void kernel_launch(void* const* d_in, const int* in_sizes, int n_in,
                              void* d_out, int out_size, void* d_ws, size_t ws_size,
                              hipStream_t stream)
{
    const float* u     = (const float*)d_in[0];
    const float* x1    = (const float*)d_in[1];
    const float* x2    = (const float*)d_in[2];
    const float* w1    = (const float*)d_in[3];
    const float* w2    = (const float*)d_in[4];
    const float* k1W0  = (const float*)d_in[5];
    const float* k1b0  = (const float*)d_in[6];
    const float* k1W1  = (const float*)d_in[7];
    const float* k1b1  = (const float*)d_in[8];
    const float* k1W2  = (const float*)d_in[9];
    const float* k1b2  = (const float*)d_in[10];
    const float* k2W0  = (const float*)d_in[11];
    const float* k2b0  = (const float*)d_in[12];
    const float* k2W1  = (const float*)d_in[13];
    const float* k2b1  = (const float*)d_in[14];
    const float* k2W2  = (const float*)d_in[15];
    const float* k2b2  = (const float*)d_in[16];

    float* out = (float*)d_out;
    float* K1buf = (float*)d_ws;                       // 1024*4096 floats = 16 MB
    float* K2buf = K1buf + (size_t)QP * NPTS;          // another 16 MB

    // Stage 1: materialize the two Khatri-Rao kernel components.
    mlp_kernel<<<dim3(512, 2), 256, 0, stream>>>(
        x1, x2,
        k1W0, k1b0, k1W1, k1b1, k1W2, k1b2,
        k2W0, k2b0, k2W1, k2b1, k2W2, k2b2,
        K1buf, K2buf);

    // Stage 2: the double mode-product, one block per (b, a).
    contract_kernel<<<dim3(B * Q), 256, 0, stream>>>(
        u, w1, w2, K1buf, K2buf, out);
}

// Round 2
// 123.221 us; speedup vs baseline: 2.5522x; 2.5522x over previous
//
#include <hip/hip_runtime.h>
#include <cmath>

namespace {

typedef short short8 __attribute__((ext_vector_type(8)));
typedef float f32x4  __attribute__((ext_vector_type(4)));

constexpr int HID  = 128;
constexpr int QP   = 1024;   // Q*P
constexpr int N    = 64;
constexpr int NPTS = 4096;   // N*N
constexpr int B    = 16;
constexpr int P    = 32;
constexpr int Q    = 32;
constexpr int LDP  = 72;     // bf16 LDS row stride: 144 B -> 4-bank rotation/row

__device__ __forceinline__ unsigned short f2bf(float x) {
    unsigned u = __float_as_uint(x);
    u += 0x7FFF + ((u >> 16) & 1);          // round-to-nearest-even
    return (unsigned short)(u >> 16);
}

__device__ __forceinline__ float gelu_tanh(float x) {
    const float c0 = 0.7978845608028654f;   // sqrt(2/pi)
    const float c1 = 0.044715f;
    float inner = c0 * (x + c1 * x * x * x);
    return 0.5f * x * (1.0f + tanhf(inner));
}

// ---------------------------------------------------------------------------
// Kernel 1: per-dimension MLP kernels on the 64x64 grid, bf16 output.
// grid (256, 2): 16 points per block (same row i, 16 consecutive j).
// Output layout: K[o*4096 + i*64 + j], o = a*P + c, bf16 bits (ushort).
// ---------------------------------------------------------------------------
__global__ __launch_bounds__(256)
void mlp_kernel(const float* __restrict__ xs1, const float* __restrict__ xs2,
                const float* __restrict__ W0a, const float* __restrict__ b0a,
                const float* __restrict__ W1a, const float* __restrict__ b1a,
                const float* __restrict__ W2a, const float* __restrict__ b2a,
                const float* __restrict__ W0b, const float* __restrict__ b0b,
                const float* __restrict__ W1b, const float* __restrict__ b1b,
                const float* __restrict__ W2b, const float* __restrict__ b2b,
                unsigned short* __restrict__ K1out, unsigned short* __restrict__ K2out)
{
    const int dim = blockIdx.y;
    const float* xs = dim ? xs2 : xs1;
    const float* W0 = dim ? W0b : W0a;
    const float* b0 = dim ? b0b : b0a;
    const float* W1 = dim ? W1b : W1a;
    const float* b1 = dim ? b1b : b1a;
    const float* W2 = dim ? W2b : W2a;
    const float* b2 = dim ? b2b : b2a;
    unsigned short* Kout = dim ? K2out : K1out;

    __shared__ float h0s[16][HID];
    __shared__ float h1s[16][HID];

    const int t    = threadIdx.x;
    const int ch   = t & (HID - 1);
    const int half = t >> 7;              // 0 or 1
    const int p0   = blockIdx.x * 16;     // first point of this block
    const int i    = p0 >> 6;             // row index (same for all 16 points)
    const int j0   = p0 & 63;
    const float y  = xs[i];

    // layer 0: 2 -> 128
    #pragma unroll
    for (int pass = 0; pass < 8; ++pass) {
        const int pp = pass * 2 + half;
        const float x = xs[j0 + pp];
        float v = fmaf(y, W0[ch], fmaf(x, W0[HID + ch], b0[ch]));
        h0s[pp][ch] = gelu_tanh(v);
    }
    __syncthreads();

    // layer 1: 128 -> 128, each half handles 8 points
    {
        const int pp0 = half * 8;
        const float bb = b1[ch];
        float a[8];
        #pragma unroll
        for (int e = 0; e < 8; ++e) a[e] = bb;
        for (int k = 0; k < HID; ++k) {
            const float w = W1[k * HID + ch];
            #pragma unroll
            for (int e = 0; e < 8; ++e)
                a[e] = fmaf(h0s[pp0 + e][k], w, a[e]);   // h0s read is lane-uniform: broadcast
        }
        #pragma unroll
        for (int e = 0; e < 8; ++e)
            h1s[pp0 + e][ch] = gelu_tanh(a[e]);
    }
    __syncthreads();

    // layer 2: 128 -> 1024, all 16 points per thread-channel, bf16 store
    #pragma unroll
    for (int ob = 0; ob < 4; ++ob) {
        const int o = ob * 256 + t;
        const float bb = b2[o];
        float acc[16];
        #pragma unroll
        for (int pp = 0; pp < 16; ++pp) acc[pp] = bb;
        for (int k = 0; k < HID; ++k) {
            const float w = W2[k * QP + o];
            #pragma unroll
            for (int pp = 0; pp < 16; ++pp)
                acc[pp] = fmaf(h1s[pp][k], w, acc[pp]);
        }
        unsigned short* dst = Kout + (size_t)o * NPTS + p0;
        short8 v0, v1;
        #pragma unroll
        for (int e = 0; e < 8; ++e) { v0[e] = (short)f2bf(acc[e]); v1[e] = (short)f2bf(acc[8 + e]); }
        *reinterpret_cast<short8*>(dst)     = v0;
        *reinterpret_cast<short8*>(dst + 8) = v1;
    }
}

// ---------------------------------------------------------------------------
// Kernel 2: out[b,a] = K1[a,c] @ (vw[b,c] @ K2[a,c]^T) summed over c, via
// bf16 MFMA 16x16x32.  One block per (b,a), 4 waves.
//   mm1: Z[j][k] = sum_m vw[j][m] * K2[k][m]   (A=vw natural, B=K2 natural)
//   C-frags of mm1 written transposed -> sZT[k][j] with contiguous b64 writes
//   mm2: out[i][k] += sum_j K1[i][j] * Z[j][k] (A=K1 natural, B=sZT)
// ---------------------------------------------------------------------------
__global__ __launch_bounds__(256, 4)
void contract_kernel(const float* __restrict__ u,
                     const float* __restrict__ w1,
                     const float* __restrict__ w2,
                     const unsigned short* __restrict__ K1,
                     const unsigned short* __restrict__ K2,
                     float* __restrict__ out)
{
    __shared__ unsigned short sK1[N * LDP];
    __shared__ unsigned short sK2[N * LDP];
    __shared__ unsigned short sVW[N * LDP];
    __shared__ unsigned short sZT[N * LDP];

    const int b = blockIdx.x >> 5;
    const int a = blockIdx.x & 31;
    const int t = threadIdx.x;
    const int w = t >> 6;        // wave id 0..3
    const int l = t & 63;        // lane
    const int lr = l & 15;       // MFMA row/col within tile
    const int lh = l >> 4;       // k-group 0..3

    f32x4 accO[4];
    #pragma unroll
    for (int kt = 0; kt < 4; ++kt) accO[kt] = f32x4{0.f, 0.f, 0.f, 0.f};

    for (int c = 0; c < P; ++c) {
        const unsigned short* K1p = K1 + (size_t)(a * P + c) * NPTS;
        const unsigned short* K2p = K2 + (size_t)(a * P + c) * NPTS;
        const float*          up  = u  + (size_t)(b * P + c) * NPTS;

        // ---- stage K1, K2 (bf16, coalesced uint4) ----
        #pragma unroll
        for (int p = 0; p < 2; ++p) {
            const int row = p * 32 + (t >> 3);
            const int col = (t & 7) * 8;
            uint4 v1 = reinterpret_cast<const uint4*>(K1p)[p * 256 + t];
            uint4 v2 = reinterpret_cast<const uint4*>(K2p)[p * 256 + t];
            *reinterpret_cast<uint4*>(&sK1[row * LDP + col]) = v1;
            *reinterpret_cast<uint4*>(&sK2[row * LDP + col]) = v2;
        }
        // ---- stage vw = u * (w1 outer w2), fp32 -> bf16, natural [j][m] ----
        #pragma unroll
        for (int p = 0; p < 4; ++p) {
            const int row = p * 16 + (t >> 4);   // j
            const int col = (t & 15) * 4;        // m
            float4 uv  = reinterpret_cast<const float4*>(up)[p * 256 + t];
            float4 w2v = reinterpret_cast<const float4*>(w2)[t & 15];
            const float w1v = w1[row];
            uint2 pk;
            pk.x = (unsigned)f2bf(uv.x * w1v * w2v.x) | ((unsigned)f2bf(uv.y * w1v * w2v.y) << 16);
            pk.y = (unsigned)f2bf(uv.z * w1v * w2v.z) | ((unsigned)f2bf(uv.w * w1v * w2v.w) << 16);
            *reinterpret_cast<uint2*>(&sVW[row * LDP + col]) = pk;
        }
        __syncthreads();

        // ---- mm1: Z = vw @ K2^T, write Z^T to sZT ----
        {
            short8 a0 = *reinterpret_cast<const short8*>(&sVW[(16 * w + lr) * LDP + lh * 8]);
            short8 a1 = *reinterpret_cast<const short8*>(&sVW[(16 * w + lr) * LDP + 32 + lh * 8]);
            #pragma unroll
            for (int kt = 0; kt < 4; ++kt) {
                short8 b0 = *reinterpret_cast<const short8*>(&sK2[(kt * 16 + lr) * LDP + lh * 8]);
                short8 b1 = *reinterpret_cast<const short8*>(&sK2[(kt * 16 + lr) * LDP + 32 + lh * 8]);
                f32x4 z = f32x4{0.f, 0.f, 0.f, 0.f};
                z = __builtin_amdgcn_mfma_f32_16x16x32_bf16(a0, b0, z, 0, 0, 0);
                z = __builtin_amdgcn_mfma_f32_16x16x32_bf16(a1, b1, z, 0, 0, 0);
                // lane holds Z[j = 16w + lh*4 + r][k = kt*16 + lr]; store at sZT[k][j]
                uint2 pk;
                pk.x = (unsigned)f2bf(z[0]) | ((unsigned)f2bf(z[1]) << 16);
                pk.y = (unsigned)f2bf(z[2]) | ((unsigned)f2bf(z[3]) << 16);
                *reinterpret_cast<uint2*>(&sZT[(kt * 16 + lr) * LDP + 16 * w + lh * 4]) = pk;
            }
        }
        __syncthreads();

        // ---- mm2: out += K1 @ Z ----
        {
            short8 a0 = *reinterpret_cast<const short8*>(&sK1[(16 * w + lr) * LDP + lh * 8]);
            short8 a1 = *reinterpret_cast<const short8*>(&sK1[(16 * w + lr) * LDP + 32 + lh * 8]);
            #pragma unroll
            for (int kt = 0; kt < 4; ++kt) {
                short8 b0 = *reinterpret_cast<const short8*>(&sZT[(kt * 16 + lr) * LDP + lh * 8]);
                short8 b1 = *reinterpret_cast<const short8*>(&sZT[(kt * 16 + lr) * LDP + 32 + lh * 8]);
                accO[kt] = __builtin_amdgcn_mfma_f32_16x16x32_bf16(a0, b0, accO[kt], 0, 0, 0);
                accO[kt] = __builtin_amdgcn_mfma_f32_16x16x32_bf16(a1, b1, accO[kt], 0, 0, 0);
            }
        }
        __syncthreads();
    }

    // ---- epilogue: out[b, a*4096 + i*64 + k] ----
    float* op = out + (size_t)b * (Q * NPTS) + (size_t)a * NPTS;
    #pragma unroll
    for (int kt = 0; kt < 4; ++kt)
        #pragma unroll
        for (int r = 0; r < 4; ++r)
            op[(16 * w + lh * 4 + r) * N + kt * 16 + lr] = accO[kt][r];
}

} // namespace

extern "C" void kernel_launch(void* const* d_in, const int* in_sizes, int n_in,
                              void* d_out, int out_size, void* d_ws, size_t ws_size,
                              hipStream_t stream)
{
    const float* u     = (const float*)d_in[0];
    const float* x1    = (const float*)d_in[1];
    const float* x2    = (const float*)d_in[2];
    const float* w1    = (const float*)d_in[3];
    const float* w2    = (const float*)d_in[4];
    const float* k1W0  = (const float*)d_in[5];
    const float* k1b0  = (const float*)d_in[6];
    const float* k1W1  = (const float*)d_in[7];
    const float* k1b1  = (const float*)d_in[8];
    const float* k1W2  = (const float*)d_in[9];
    const float* k1b2  = (const float*)d_in[10];
    const float* k2W0  = (const float*)d_in[11];
    const float* k2b0  = (const float*)d_in[12];
    const float* k2W1  = (const float*)d_in[13];
    const float* k2b1  = (const float*)d_in[14];
    const float* k2W2  = (const float*)d_in[15];
    const float* k2b2  = (const float*)d_in[16];

    float* out = (float*)d_out;
    unsigned short* K1buf = (unsigned short*)d_ws;          // 1024*4096 bf16 = 8 MB
    unsigned short* K2buf = K1buf + (size_t)QP * NPTS;      // another 8 MB

    mlp_kernel<<<dim3(256, 2), 256, 0, stream>>>(
        x1, x2,
        k1W0, k1b0, k1W1, k1b1, k1W2, k1b2,
        k2W0, k2b0, k2W1, k2b1, k2W2, k2b2,
        K1buf, K2buf);

    contract_kernel<<<dim3(B * Q), 256, 0, stream>>>(
        u, w1, w2, K1buf, K2buf, out);
}

// Round 3
// 83.122 us; speedup vs baseline: 3.7834x; 1.4824x over previous
//
#include <hip/hip_runtime.h>
#include <cmath>

namespace {

typedef short short8 __attribute__((ext_vector_type(8)));
typedef float f32x4  __attribute__((ext_vector_type(4)));
typedef unsigned short ushort;

constexpr int HID  = 128;
constexpr int QP   = 1024;   // Q*P
constexpr int N    = 64;
constexpr int NPTS = 4096;   // N*N
constexpr int B    = 16;
constexpr int P    = 32;
constexpr int Q    = 32;
constexpr int LDP  = 72;     // contract LDS stride (bf16): 144 B -> 4-bank rotation
constexpr int LDH  = 136;    // mlp h LDS stride (bf16):   272 B -> 4-bank rotation

__device__ __forceinline__ ushort f2bf(float x) {
    unsigned u = __float_as_uint(x);
    u += 0x7FFF + ((u >> 16) & 1);          // round-to-nearest-even
    return (ushort)(u >> 16);
}
__device__ __forceinline__ float bf2f(ushort b) {
    return __uint_as_float((unsigned)b << 16);
}
__device__ __forceinline__ float gelu_tanh(float x) {
    const float c0 = 0.7978845608028654f;   // sqrt(2/pi)
    const float c1 = 0.044715f;
    float inner = c0 * (x + c1 * x * x * x);
    return 0.5f * x * (1.0f + tanhf(inner));
}

// ---------------------------------------------------------------------------
// Kernel 0: transpose + split-bf16 the MLP weights.
//   W1T[dim][c_out][k_in]  (h & l),  W2T[dim][o][k]  (h & l)
// ---------------------------------------------------------------------------
__global__ __launch_bounds__(256)
void wsplit_kernel(const float* __restrict__ W1a, const float* __restrict__ W2a,
                   const float* __restrict__ W1b, const float* __restrict__ W2b,
                   ushort* __restrict__ W1Th, ushort* __restrict__ W1Tl,
                   ushort* __restrict__ W2Th, ushort* __restrict__ W2Tl)
{
    const int g   = blockIdx.x * 256 + threadIdx.x;   // 0 .. 2*147456-1
    const int dim = g / 147456;
    const int r   = g - dim * 147456;
    const float* W1 = dim ? W1b : W1a;
    const float* W2 = dim ? W2b : W2a;
    float v; ushort *dh, *dl; int idx;
    if (r < 16384) {                 // W1T: o=c_out, k=k_in
        const int o = r >> 7, k = r & 127;
        v = W1[k * HID + o];
        idx = dim * 16384 + r;
        dh = W1Th; dl = W1Tl;
    } else {
        const int r2 = r - 16384;    // W2T
        const int o = r2 >> 7, k = r2 & 127;
        v = W2[k * QP + o];
        idx = dim * 131072 + r2;
        dh = W2Th; dl = W2Tl;
    }
    const ushort h = f2bf(v);
    const ushort l = f2bf(v - bf2f(h));
    dh[idx] = h; dl[idx] = l;
}

// ---------------------------------------------------------------------------
// Kernel 1: MLP kernels via split-bf16 MFMA.
// grid (64, 2, 2): x = grid row i (64 points j), y = dim, z = o-half (512 o's).
// Layers 0/1 produce h0,h1 (split) in LDS [pt][k]; layer 2 is MFMA with
// A = h1 (LDS), B = W2T (global), D[pt][o] -> coalesced 8B bf16 stores.
// Fragment convention (verified in R2): frag = buf[(tile*16 + l&15)*LD + kk*32
// + (l>>4)*8], D[Arow_tile + (l>>4)*4 + reg][Brow_tile + (l&15)].
// ---------------------------------------------------------------------------
__global__ __launch_bounds__(256, 1)
void mlp_kernel(const float* __restrict__ xs1, const float* __restrict__ xs2,
                const float* __restrict__ W0a, const float* __restrict__ b0a,
                const float* __restrict__ b1a, const float* __restrict__ b2a,
                const float* __restrict__ W0b, const float* __restrict__ b0b,
                const float* __restrict__ b1b, const float* __restrict__ b2b,
                const ushort* __restrict__ W1Th, const ushort* __restrict__ W1Tl,
                const ushort* __restrict__ W2Th, const ushort* __restrict__ W2Tl,
                ushort* __restrict__ K1out, ushort* __restrict__ K2out)
{
    __shared__ ushort h0h[N * LDH], h0l[N * LDH];
    __shared__ ushort h1h[N * LDH], h1l[N * LDH];

    const int i   = blockIdx.x;       // grid row (y coordinate index)
    const int dim = blockIdx.y;
    const int bz  = blockIdx.z;       // o-half
    const float* xs = dim ? xs2 : xs1;
    const float* W0 = dim ? W0b : W0a;
    const float* b0 = dim ? b0b : b0a;
    const float* b1 = dim ? b1b : b1a;
    const float* b2 = dim ? b2b : b2a;
    const ushort* w1h = W1Th + dim * 16384;
    const ushort* w1l = W1Tl + dim * 16384;
    const ushort* w2h = W2Th + dim * 131072;
    const ushort* w2l = W2Tl + dim * 131072;
    ushort* Kout = dim ? K2out : K1out;

    const int t  = threadIdx.x;
    const int w  = t >> 6;
    const int l  = t & 63;
    const int lr = l & 15;
    const int lh = l >> 4;
    const float y = xs[i];

    // ---- layer 0: 2 -> 128, fp32 then split to bf16 h+l ----
    {
        const int ch    = t & 127;
        const int pbase = (t >> 7) * 32;
        const float wy = W0[ch], wx = W0[HID + ch], bb = b0[ch];
        for (int pp = 0; pp < 32; ++pp) {
            const int pt = pbase + pp;
            const float z = fmaf(y, wy, fmaf(xs[pt], wx, bb));
            const float h = gelu_tanh(z);
            const ushort hb = f2bf(h);
            h0h[pt * LDH + ch] = hb;
            h0l[pt * LDH + ch] = f2bf(h - bf2f(hb));
        }
    }
    __syncthreads();

    // ---- layer 1: 128 -> 128 via 3-term split MFMA; gelu; write h1 ----
    {
        #pragma unroll
        for (int cc = 0; cc < 2; ++cc) {
            const int ct = w * 2 + cc;                 // c_out tile
            const ushort* ap = w1h + (ct * 16 + lr) * HID + lh * 8;
            const ushort* aq = w1l + (ct * 16 + lr) * HID + lh * 8;
            short8 Ah[4], Al[4];
            #pragma unroll
            for (int kk = 0; kk < 4; ++kk) {
                Ah[kk] = *reinterpret_cast<const short8*>(ap + kk * 32);
                Al[kk] = *reinterpret_cast<const short8*>(aq + kk * 32);
            }
            f32x4 acc[4];
            #pragma unroll
            for (int p = 0; p < 4; ++p) acc[p] = f32x4{0.f, 0.f, 0.f, 0.f};
            #pragma unroll
            for (int kk = 0; kk < 4; ++kk) {
                short8 Bh[4], Bl[4];
                #pragma unroll
                for (int p = 0; p < 4; ++p) {
                    Bh[p] = *reinterpret_cast<const short8*>(&h0h[(p * 16 + lr) * LDH + kk * 32 + lh * 8]);
                    Bl[p] = *reinterpret_cast<const short8*>(&h0l[(p * 16 + lr) * LDH + kk * 32 + lh * 8]);
                }
                #pragma unroll
                for (int p = 0; p < 4; ++p)
                    acc[p] = __builtin_amdgcn_mfma_f32_16x16x32_bf16(Ah[kk], Bh[p], acc[p], 0, 0, 0);
                #pragma unroll
                for (int p = 0; p < 4; ++p)
                    acc[p] = __builtin_amdgcn_mfma_f32_16x16x32_bf16(Al[kk], Bh[p], acc[p], 0, 0, 0);
                #pragma unroll
                for (int p = 0; p < 4; ++p)
                    acc[p] = __builtin_amdgcn_mfma_f32_16x16x32_bf16(Ah[kk], Bl[p], acc[p], 0, 0, 0);
            }
            // epilogue: bias + gelu + split, write h1[pt][c] (8B per lane)
            const float4 bb = *reinterpret_cast<const float4*>(&b1[ct * 16 + lh * 4]);
            #pragma unroll
            for (int p = 0; p < 4; ++p) {
                ushort hb[4], lb[4];
                #pragma unroll
                for (int r = 0; r < 4; ++r) {
                    const float zv = acc[p][r] + ((const float*)&bb)[r];
                    const float h  = gelu_tanh(zv);
                    hb[r] = f2bf(h);
                    lb[r] = f2bf(h - bf2f(hb[r]));
                }
                uint2 ph, pl;
                ph.x = (unsigned)hb[0] | ((unsigned)hb[1] << 16);
                ph.y = (unsigned)hb[2] | ((unsigned)hb[3] << 16);
                pl.x = (unsigned)lb[0] | ((unsigned)lb[1] << 16);
                pl.y = (unsigned)lb[2] | ((unsigned)lb[3] << 16);
                const int off = (p * 16 + lr) * LDH + ct * 16 + lh * 4;
                *reinterpret_cast<uint2*>(&h1h[off]) = ph;
                *reinterpret_cast<uint2*>(&h1l[off]) = pl;
            }
        }
    }
    __syncthreads();

    // ---- layer 2: 128 -> 1024 (this block: 512 o's) via 3-term split MFMA ----
    {
        short8 Ah[4][4], Al[4][4];   // h1 fragments: [pt-tile][kk]
        #pragma unroll
        for (int p = 0; p < 4; ++p)
            #pragma unroll
            for (int kk = 0; kk < 4; ++kk) {
                Ah[p][kk] = *reinterpret_cast<const short8*>(&h1h[(p * 16 + lr) * LDH + kk * 32 + lh * 8]);
                Al[p][kk] = *reinterpret_cast<const short8*>(&h1l[(p * 16 + lr) * LDH + kk * 32 + lh * 8]);
            }

        const int otbase = bz * 32 + w * 8;

#define LOADB(BH, BL, OT) do {                                                      \
        const ushort* _p = w2h + (size_t)((OT) * 16 + lr) * HID + lh * 8;           \
        const ushort* _q = w2l + (size_t)((OT) * 16 + lr) * HID + lh * 8;           \
        _Pragma("unroll")                                                           \
        for (int kk = 0; kk < 4; ++kk) {                                            \
            BH[kk] = *reinterpret_cast<const short8*>(_p + kk * 32);                \
            BL[kk] = *reinterpret_cast<const short8*>(_q + kk * 32);                \
        } } while (0)

#define MMTILE(BH, BL, OT) do {                                                     \
        f32x4 acc[4];                                                               \
        _Pragma("unroll")                                                           \
        for (int p = 0; p < 4; ++p) acc[p] = f32x4{0.f, 0.f, 0.f, 0.f};             \
        _Pragma("unroll")                                                           \
        for (int kk = 0; kk < 4; ++kk) {                                            \
            _Pragma("unroll")                                                       \
            for (int p = 0; p < 4; ++p)                                             \
                acc[p] = __builtin_amdgcn_mfma_f32_16x16x32_bf16(Ah[p][kk], BH[kk], acc[p], 0, 0, 0); \
            _Pragma("unroll")                                                       \
            for (int p = 0; p < 4; ++p)                                             \
                acc[p] = __builtin_amdgcn_mfma_f32_16x16x32_bf16(Al[p][kk], BH[kk], acc[p], 0, 0, 0); \
            _Pragma("unroll")                                                       \
            for (int p = 0; p < 4; ++p)                                             \
                acc[p] = __builtin_amdgcn_mfma_f32_16x16x32_bf16(Ah[p][kk], BL[kk], acc[p], 0, 0, 0); \
        }                                                                           \
        const int _o = (OT) * 16 + lr;                                              \
        const float _bo = b2[_o];                                                   \
        ushort* _d = Kout + (size_t)_o * NPTS + i * 64 + lh * 4;                    \
        _Pragma("unroll")                                                           \
        for (int p = 0; p < 4; ++p) {                                               \
            uint2 pk;                                                               \
            pk.x = (unsigned)f2bf(acc[p][0] + _bo) | ((unsigned)f2bf(acc[p][1] + _bo) << 16); \
            pk.y = (unsigned)f2bf(acc[p][2] + _bo) | ((unsigned)f2bf(acc[p][3] + _bo) << 16); \
            *reinterpret_cast<uint2*>(_d + p * 16) = pk;                            \
        } } while (0)

        short8 B0h[4], B0l[4], B1h[4], B1l[4];
        LOADB(B0h, B0l, otbase + 0);
        #pragma unroll
        for (int oo = 0; oo < 8; oo += 2) {
            if (oo + 1 < 8) LOADB(B1h, B1l, otbase + oo + 1);
            MMTILE(B0h, B0l, otbase + oo);
            if (oo + 2 < 8) LOADB(B0h, B0l, otbase + oo + 2);
            MMTILE(B1h, B1l, otbase + oo + 1);
        }
#undef LOADB
#undef MMTILE
    }
}

// ---------------------------------------------------------------------------
// Kernel 2: out[b,a] = K1[a,c] @ (vw[b,c] @ K2[a,c]^T) summed over c (MFMA).
// Unchanged from R2.
// ---------------------------------------------------------------------------
__global__ __launch_bounds__(256, 4)
void contract_kernel(const float* __restrict__ u,
                     const float* __restrict__ w1,
                     const float* __restrict__ w2,
                     const ushort* __restrict__ K1,
                     const ushort* __restrict__ K2,
                     float* __restrict__ out)
{
    __shared__ ushort sK1[N * LDP];
    __shared__ ushort sK2[N * LDP];
    __shared__ ushort sVW[N * LDP];
    __shared__ ushort sZT[N * LDP];

    const int b = blockIdx.x >> 5;
    const int a = blockIdx.x & 31;
    const int t = threadIdx.x;
    const int w = t >> 6;
    const int l = t & 63;
    const int lr = l & 15;
    const int lh = l >> 4;

    f32x4 accO[4];
    #pragma unroll
    for (int kt = 0; kt < 4; ++kt) accO[kt] = f32x4{0.f, 0.f, 0.f, 0.f};

    for (int c = 0; c < P; ++c) {
        const ushort* K1p = K1 + (size_t)(a * P + c) * NPTS;
        const ushort* K2p = K2 + (size_t)(a * P + c) * NPTS;
        const float*  up  = u  + (size_t)(b * P + c) * NPTS;

        #pragma unroll
        for (int p = 0; p < 2; ++p) {
            const int row = p * 32 + (t >> 3);
            const int col = (t & 7) * 8;
            uint4 v1 = reinterpret_cast<const uint4*>(K1p)[p * 256 + t];
            uint4 v2 = reinterpret_cast<const uint4*>(K2p)[p * 256 + t];
            *reinterpret_cast<uint4*>(&sK1[row * LDP + col]) = v1;
            *reinterpret_cast<uint4*>(&sK2[row * LDP + col]) = v2;
        }
        #pragma unroll
        for (int p = 0; p < 4; ++p) {
            const int row = p * 16 + (t >> 4);
            const int col = (t & 15) * 4;
            float4 uv  = reinterpret_cast<const float4*>(up)[p * 256 + t];
            float4 w2v = reinterpret_cast<const float4*>(w2)[t & 15];
            const float w1v = w1[row];
            uint2 pk;
            pk.x = (unsigned)f2bf(uv.x * w1v * w2v.x) | ((unsigned)f2bf(uv.y * w1v * w2v.y) << 16);
            pk.y = (unsigned)f2bf(uv.z * w1v * w2v.z) | ((unsigned)f2bf(uv.w * w1v * w2v.w) << 16);
            *reinterpret_cast<uint2*>(&sVW[row * LDP + col]) = pk;
        }
        __syncthreads();

        {   // mm1: Z = vw @ K2^T, write Z^T
            short8 a0 = *reinterpret_cast<const short8*>(&sVW[(16 * w + lr) * LDP + lh * 8]);
            short8 a1 = *reinterpret_cast<const short8*>(&sVW[(16 * w + lr) * LDP + 32 + lh * 8]);
            #pragma unroll
            for (int kt = 0; kt < 4; ++kt) {
                short8 b0 = *reinterpret_cast<const short8*>(&sK2[(kt * 16 + lr) * LDP + lh * 8]);
                short8 b1 = *reinterpret_cast<const short8*>(&sK2[(kt * 16 + lr) * LDP + 32 + lh * 8]);
                f32x4 z = f32x4{0.f, 0.f, 0.f, 0.f};
                z = __builtin_amdgcn_mfma_f32_16x16x32_bf16(a0, b0, z, 0, 0, 0);
                z = __builtin_amdgcn_mfma_f32_16x16x32_bf16(a1, b1, z, 0, 0, 0);
                uint2 pk;
                pk.x = (unsigned)f2bf(z[0]) | ((unsigned)f2bf(z[1]) << 16);
                pk.y = (unsigned)f2bf(z[2]) | ((unsigned)f2bf(z[3]) << 16);
                *reinterpret_cast<uint2*>(&sZT[(kt * 16 + lr) * LDP + 16 * w + lh * 4]) = pk;
            }
        }
        __syncthreads();

        {   // mm2: out += K1 @ Z
            short8 a0 = *reinterpret_cast<const short8*>(&sK1[(16 * w + lr) * LDP + lh * 8]);
            short8 a1 = *reinterpret_cast<const short8*>(&sK1[(16 * w + lr) * LDP + 32 + lh * 8]);
            #pragma unroll
            for (int kt = 0; kt < 4; ++kt) {
                short8 b0 = *reinterpret_cast<const short8*>(&sZT[(kt * 16 + lr) * LDP + lh * 8]);
                short8 b1 = *reinterpret_cast<const short8*>(&sZT[(kt * 16 + lr) * LDP + 32 + lh * 8]);
                accO[kt] = __builtin_amdgcn_mfma_f32_16x16x32_bf16(a0, b0, accO[kt], 0, 0, 0);
                accO[kt] = __builtin_amdgcn_mfma_f32_16x16x32_bf16(a1, b1, accO[kt], 0, 0, 0);
            }
        }
        __syncthreads();
    }

    float* op = out + (size_t)b * (Q * NPTS) + (size_t)a * NPTS;
    #pragma unroll
    for (int kt = 0; kt < 4; ++kt)
        #pragma unroll
        for (int r = 0; r < 4; ++r)
            op[(16 * w + lh * 4 + r) * N + kt * 16 + lr] = accO[kt][r];
}

} // namespace

extern "C" void kernel_launch(void* const* d_in, const int* in_sizes, int n_in,
                              void* d_out, int out_size, void* d_ws, size_t ws_size,
                              hipStream_t stream)
{
    const float* u     = (const float*)d_in[0];
    const float* x1    = (const float*)d_in[1];
    const float* x2    = (const float*)d_in[2];
    const float* w1    = (const float*)d_in[3];
    const float* w2    = (const float*)d_in[4];
    const float* k1W0  = (const float*)d_in[5];
    const float* k1b0  = (const float*)d_in[6];
    const float* k1W1  = (const float*)d_in[7];
    const float* k1b1  = (const float*)d_in[8];
    const float* k1W2  = (const float*)d_in[9];
    const float* k1b2  = (const float*)d_in[10];
    const float* k2W0  = (const float*)d_in[11];
    const float* k2b0  = (const float*)d_in[12];
    const float* k2W1  = (const float*)d_in[13];
    const float* k2b1  = (const float*)d_in[14];
    const float* k2W2  = (const float*)d_in[15];
    const float* k2b2  = (const float*)d_in[16];

    float* out = (float*)d_out;
    ushort* ws = (ushort*)d_ws;
    ushort* K1buf = ws;                                   // 4M ushorts (8 MB)
    ushort* K2buf = ws + (size_t)QP * NPTS;               // 4M
    ushort* W2Th  = ws + 2 * (size_t)QP * NPTS;           // 2*131072
    ushort* W2Tl  = W2Th + 2 * 131072;
    ushort* W1Th  = W2Tl + 2 * 131072;                    // 2*16384
    ushort* W1Tl  = W1Th + 2 * 16384;

    wsplit_kernel<<<dim3(1152), 256, 0, stream>>>(
        k1W1, k1W2, k2W1, k2W2, W1Th, W1Tl, W2Th, W2Tl);

    mlp_kernel<<<dim3(64, 2, 2), 256, 0, stream>>>(
        x1, x2,
        k1W0, k1b0, k1b1, k1b2,
        k2W0, k2b0, k2b1, k2b2,
        W1Th, W1Tl, W2Th, W2Tl,
        K1buf, K2buf);

    contract_kernel<<<dim3(B * Q), 256, 0, stream>>>(
        u, w1, w2, K1buf, K2buf, out);
}

// Round 4
// 70.936 us; speedup vs baseline: 4.4334x; 1.1718x over previous
//
#include <hip/hip_runtime.h>
#include <cmath>

namespace {

typedef short short8 __attribute__((ext_vector_type(8)));
typedef float f32x4  __attribute__((ext_vector_type(4)));
typedef unsigned short ushort;

constexpr int HID  = 128;
constexpr int QP   = 1024;   // Q*P
constexpr int N    = 64;
constexpr int NPTS = 4096;   // N*N
constexpr int B    = 16;
constexpr int P    = 32;
constexpr int Q    = 32;
constexpr int LDH  = 136;    // mlp h LDS stride (bf16)
constexpr int CH   = 4;      // contract c-split factor
constexpr int CCH  = P / CH; // 8 c per contract block

__device__ __forceinline__ ushort f2bf(float x) {
    unsigned u = __float_as_uint(x);
    u += 0x7FFF + ((u >> 16) & 1);          // round-to-nearest-even
    return (ushort)(u >> 16);
}
__device__ __forceinline__ float bf2f(ushort b) {
    return __uint_as_float((unsigned)b << 16);
}
__device__ __forceinline__ float gelu_tanh(float x) {
    const float c0 = 0.7978845608028654f;   // sqrt(2/pi)
    const float c1 = 0.044715f;
    float inner = c0 * (x + c1 * x * x * x);
    return 0.5f * x * (1.0f + tanhf(inner));
}

__device__ __forceinline__ void gll16(const ushort* src, ushort* dst) {
    __builtin_amdgcn_global_load_lds(
        (const __attribute__((address_space(1))) unsigned int*)src,
        (__attribute__((address_space(3))) unsigned int*)dst, 16, 0, 0);
}

// ---------------------------------------------------------------------------
// Kernel 0: transpose + split-bf16 the MLP weights (unchanged from R3).
// ---------------------------------------------------------------------------
__global__ __launch_bounds__(256)
void wsplit_kernel(const float* __restrict__ W1a, const float* __restrict__ W2a,
                   const float* __restrict__ W1b, const float* __restrict__ W2b,
                   ushort* __restrict__ W1Th, ushort* __restrict__ W1Tl,
                   ushort* __restrict__ W2Th, ushort* __restrict__ W2Tl)
{
    const int g   = blockIdx.x * 256 + threadIdx.x;   // 0 .. 2*147456-1
    const int dim = g / 147456;
    const int r   = g - dim * 147456;
    const float* W1 = dim ? W1b : W1a;
    const float* W2 = dim ? W2b : W2a;
    float v; ushort *dh, *dl; int idx;
    if (r < 16384) {                 // W1T
        const int o = r >> 7, k = r & 127;
        v = W1[k * HID + o];
        idx = dim * 16384 + r;
        dh = W1Th; dl = W1Tl;
    } else {                          // W2T
        const int r2 = r - 16384;
        const int o = r2 >> 7, k = r2 & 127;
        v = W2[k * QP + o];
        idx = dim * 131072 + r2;
        dh = W2Th; dl = W2Tl;
    }
    const ushort h = f2bf(v);
    const ushort l = f2bf(v - bf2f(h));
    dh[idx] = h; dl[idx] = l;
}

// ---------------------------------------------------------------------------
// Kernel 0b: u (fp32) -> bf16, same flat layout.
// ---------------------------------------------------------------------------
__global__ __launch_bounds__(256)
void ucvt_kernel(const float* __restrict__ u, ushort* __restrict__ ubf)
{
    const int g = blockIdx.x * 256 + threadIdx.x;     // float4 index
    const float4 v = reinterpret_cast<const float4*>(u)[g];
    uint2 pk;
    pk.x = (unsigned)f2bf(v.x) | ((unsigned)f2bf(v.y) << 16);
    pk.y = (unsigned)f2bf(v.z) | ((unsigned)f2bf(v.w) << 16);
    reinterpret_cast<uint2*>(ubf)[g] = pk;
}

// ---------------------------------------------------------------------------
// Kernel 1: MLP kernels via split-bf16 MFMA (R3 structure) + quadrature-weight
// fold: K1w = K1 * w1[col], K2w = K2 * w2[col].
// ---------------------------------------------------------------------------
__global__ __launch_bounds__(256, 1)
void mlp_kernel(const float* __restrict__ xs1, const float* __restrict__ xs2,
                const float* __restrict__ W0a, const float* __restrict__ b0a,
                const float* __restrict__ b1a, const float* __restrict__ b2a,
                const float* __restrict__ W0b, const float* __restrict__ b0b,
                const float* __restrict__ b1b, const float* __restrict__ b2b,
                const ushort* __restrict__ W1Th, const ushort* __restrict__ W1Tl,
                const ushort* __restrict__ W2Th, const ushort* __restrict__ W2Tl,
                const float* __restrict__ qw1, const float* __restrict__ qw2,
                ushort* __restrict__ K1out, ushort* __restrict__ K2out)
{
    __shared__ ushort h0h[N * LDH], h0l[N * LDH];
    __shared__ ushort h1h[N * LDH], h1l[N * LDH];

    const int i   = blockIdx.x;       // grid row
    const int dim = blockIdx.y;
    const int bz  = blockIdx.z;       // o-half
    const float* xs = dim ? xs2 : xs1;
    const float* W0 = dim ? W0b : W0a;
    const float* b0 = dim ? b0b : b0a;
    const float* b1 = dim ? b1b : b1a;
    const float* b2 = dim ? b2b : b2a;
    const float* wq = dim ? qw2 : qw1;
    const ushort* w1h = W1Th + dim * 16384;
    const ushort* w1l = W1Tl + dim * 16384;
    const ushort* w2h = W2Th + dim * 131072;
    const ushort* w2l = W2Tl + dim * 131072;
    ushort* Kout = dim ? K2out : K1out;

    const int t  = threadIdx.x;
    const int w  = t >> 6;
    const int l  = t & 63;
    const int lr = l & 15;
    const int lh = l >> 4;
    const float y = xs[i];

    // ---- layer 0 ----
    {
        const int ch    = t & 127;
        const int pbase = (t >> 7) * 32;
        const float wy = W0[ch], wx = W0[HID + ch], bb = b0[ch];
        for (int pp = 0; pp < 32; ++pp) {
            const int pt = pbase + pp;
            const float z = fmaf(y, wy, fmaf(xs[pt], wx, bb));
            const float h = gelu_tanh(z);
            const ushort hb = f2bf(h);
            h0h[pt * LDH + ch] = hb;
            h0l[pt * LDH + ch] = f2bf(h - bf2f(hb));
        }
    }
    __syncthreads();

    // ---- layer 1 ----
    {
        #pragma unroll
        for (int cc = 0; cc < 2; ++cc) {
            const int ct = w * 2 + cc;
            const ushort* ap = w1h + (ct * 16 + lr) * HID + lh * 8;
            const ushort* aq = w1l + (ct * 16 + lr) * HID + lh * 8;
            short8 Ah[4], Al[4];
            #pragma unroll
            for (int kk = 0; kk < 4; ++kk) {
                Ah[kk] = *reinterpret_cast<const short8*>(ap + kk * 32);
                Al[kk] = *reinterpret_cast<const short8*>(aq + kk * 32);
            }
            f32x4 acc[4];
            #pragma unroll
            for (int p = 0; p < 4; ++p) acc[p] = f32x4{0.f, 0.f, 0.f, 0.f};
            #pragma unroll
            for (int kk = 0; kk < 4; ++kk) {
                short8 Bh[4], Bl[4];
                #pragma unroll
                for (int p = 0; p < 4; ++p) {
                    Bh[p] = *reinterpret_cast<const short8*>(&h0h[(p * 16 + lr) * LDH + kk * 32 + lh * 8]);
                    Bl[p] = *reinterpret_cast<const short8*>(&h0l[(p * 16 + lr) * LDH + kk * 32 + lh * 8]);
                }
                #pragma unroll
                for (int p = 0; p < 4; ++p)
                    acc[p] = __builtin_amdgcn_mfma_f32_16x16x32_bf16(Ah[kk], Bh[p], acc[p], 0, 0, 0);
                #pragma unroll
                for (int p = 0; p < 4; ++p)
                    acc[p] = __builtin_amdgcn_mfma_f32_16x16x32_bf16(Al[kk], Bh[p], acc[p], 0, 0, 0);
                #pragma unroll
                for (int p = 0; p < 4; ++p)
                    acc[p] = __builtin_amdgcn_mfma_f32_16x16x32_bf16(Ah[kk], Bl[p], acc[p], 0, 0, 0);
            }
            const float4 bb = *reinterpret_cast<const float4*>(&b1[ct * 16 + lh * 4]);
            #pragma unroll
            for (int p = 0; p < 4; ++p) {
                ushort hb[4], lb[4];
                #pragma unroll
                for (int r = 0; r < 4; ++r) {
                    const float zv = acc[p][r] + ((const float*)&bb)[r];
                    const float h  = gelu_tanh(zv);
                    hb[r] = f2bf(h);
                    lb[r] = f2bf(h - bf2f(hb[r]));
                }
                uint2 ph, pl;
                ph.x = (unsigned)hb[0] | ((unsigned)hb[1] << 16);
                ph.y = (unsigned)hb[2] | ((unsigned)hb[3] << 16);
                pl.x = (unsigned)lb[0] | ((unsigned)lb[1] << 16);
                pl.y = (unsigned)lb[2] | ((unsigned)lb[3] << 16);
                const int off = (p * 16 + lr) * LDH + ct * 16 + lh * 4;
                *reinterpret_cast<uint2*>(&h1h[off]) = ph;
                *reinterpret_cast<uint2*>(&h1l[off]) = pl;
            }
        }
    }
    __syncthreads();

    // ---- layer 2 (+ bias + quadrature fold) ----
    {
        short8 Ah[4][4], Al[4][4];
        #pragma unroll
        for (int p = 0; p < 4; ++p)
            #pragma unroll
            for (int kk = 0; kk < 4; ++kk) {
                Ah[p][kk] = *reinterpret_cast<const short8*>(&h1h[(p * 16 + lr) * LDH + kk * 32 + lh * 8]);
                Al[p][kk] = *reinterpret_cast<const short8*>(&h1l[(p * 16 + lr) * LDH + kk * 32 + lh * 8]);
            }

        const int otbase = bz * 32 + w * 8;

#define LOADB(BH, BL, OT) do {                                                      \
        const ushort* _p = w2h + (size_t)((OT) * 16 + lr) * HID + lh * 8;           \
        const ushort* _q = w2l + (size_t)((OT) * 16 + lr) * HID + lh * 8;           \
        _Pragma("unroll")                                                           \
        for (int kk = 0; kk < 4; ++kk) {                                            \
            BH[kk] = *reinterpret_cast<const short8*>(_p + kk * 32);                \
            BL[kk] = *reinterpret_cast<const short8*>(_q + kk * 32);                \
        } } while (0)

#define MMTILE(BH, BL, OT) do {                                                     \
        f32x4 acc[4];                                                               \
        _Pragma("unroll")                                                           \
        for (int p = 0; p < 4; ++p) acc[p] = f32x4{0.f, 0.f, 0.f, 0.f};             \
        _Pragma("unroll")                                                           \
        for (int kk = 0; kk < 4; ++kk) {                                            \
            _Pragma("unroll")                                                       \
            for (int p = 0; p < 4; ++p)                                             \
                acc[p] = __builtin_amdgcn_mfma_f32_16x16x32_bf16(Ah[p][kk], BH[kk], acc[p], 0, 0, 0); \
            _Pragma("unroll")                                                       \
            for (int p = 0; p < 4; ++p)                                             \
                acc[p] = __builtin_amdgcn_mfma_f32_16x16x32_bf16(Al[p][kk], BH[kk], acc[p], 0, 0, 0); \
            _Pragma("unroll")                                                       \
            for (int p = 0; p < 4; ++p)                                             \
                acc[p] = __builtin_amdgcn_mfma_f32_16x16x32_bf16(Ah[p][kk], BL[kk], acc[p], 0, 0, 0); \
        }                                                                           \
        const int _o = (OT) * 16 + lr;                                              \
        const float _bo = b2[_o];                                                   \
        ushort* _d = Kout + (size_t)_o * NPTS + i * 64 + lh * 4;                    \
        _Pragma("unroll")                                                           \
        for (int p = 0; p < 4; ++p) {                                               \
            const float4 _wv = *reinterpret_cast<const float4*>(wq + p * 16 + lh * 4); \
            uint2 pk;                                                               \
            pk.x = (unsigned)f2bf((acc[p][0] + _bo) * _wv.x) |                      \
                   ((unsigned)f2bf((acc[p][1] + _bo) * _wv.y) << 16);               \
            pk.y = (unsigned)f2bf((acc[p][2] + _bo) * _wv.z) |                      \
                   ((unsigned)f2bf((acc[p][3] + _bo) * _wv.w) << 16);               \
            *reinterpret_cast<uint2*>(_d + p * 16) = pk;                            \
        } } while (0)

        short8 B0h[4], B0l[4], B1h[4], B1l[4];
        LOADB(B0h, B0l, otbase + 0);
        #pragma unroll
        for (int oo = 0; oo < 8; oo += 2) {
            if (oo + 1 < 8) LOADB(B1h, B1l, otbase + oo + 1);
            MMTILE(B0h, B0l, otbase + oo);
            if (oo + 2 < 8) LOADB(B0h, B0l, otbase + oo + 2);
            MMTILE(B1h, B1l, otbase + oo + 1);
        }
#undef LOADB
#undef MMTILE
    }
}

// ---------------------------------------------------------------------------
// Kernel 2: contract, v4.
// Grid 512 = 4bg x 32a x 4ch (after XCD swizzle). 4 waves; wave w owns
// b = bg*4+w and computes its FULL 64x64 output tile over c in [ch*8, ch*8+8).
// K1w/K2w double-buffer staged via global_load_lds with source pre-swizzle
// (granule ^= row&7); u-fragments read direct from global (bf16, L2-hot);
// per-wave sZT transpose buffer (no cross-wave hazard). One barrier per c.
// ---------------------------------------------------------------------------
__global__ __launch_bounds__(256, 2)
void contract_kernel(const ushort* __restrict__ ubf,
                     const ushort* __restrict__ K1,   // w1-folded
                     const ushort* __restrict__ K2,   // w2-folded
                     float* __restrict__ part)
{
    __shared__ ushort sK1[2][4096];
    __shared__ ushort sK2[2][4096];
    __shared__ ushort sZT[4][4096];

    // bijective XCD chunk swizzle: 512 = 8 * 64
    const int id0 = blockIdx.x;
    const int id  = (id0 & 7) * 64 + (id0 >> 3);
    const int bg  = id & 3;
    const int a   = (id >> 2) & 31;
    const int ch  = id >> 7;

    const int t  = threadIdx.x;
    const int w  = t >> 6;
    const int l  = t & 63;
    const int lr = l & 15;
    const int lh = l >> 4;
    const int b  = bg * 4 + w;
    const int c0 = ch * CCH;

    ushort* zt = &sZT[w][0];

#define STAGE(NB, CC) do {                                                      \
        const ushort* _k1 = K1 + (((size_t)a * P + (CC)) << 12);                \
        const ushort* _k2 = K2 + (((size_t)a * P + (CC)) << 12);                \
        const int _sc = (((l & 7) ^ (l >> 3)) << 3);                            \
        _Pragma("unroll")                                                       \
        for (int _i = 0; _i < 2; ++_i) {                                        \
            const int _row = 16 * w + 8 * _i + (l >> 3);                        \
            gll16(_k1 + _row * 64 + _sc, &sK1[NB][w * 1024 + _i * 512]);        \
            gll16(_k2 + _row * 64 + _sc, &sK2[NB][w * 1024 + _i * 512]);        \
        } } while (0)

    f32x4 oacc[4][4];
    #pragma unroll
    for (int it = 0; it < 4; ++it)
        #pragma unroll
        for (int kt = 0; kt < 4; ++kt) oacc[it][kt] = f32x4{0.f, 0.f, 0.f, 0.f};

    STAGE(0, c0);
    __syncthreads();

    for (int c = 0; c < CCH; ++c) {
        const int cur = c & 1;
        if (c + 1 < CCH) STAGE(cur ^ 1, c0 + c + 1);
        const int cc = c0 + c;

        // ---- mm1: Z[j][k] = sum_m ubf[j][m] * K2w[k][m] ----
        const ushort* up = ubf + (((size_t)b * P + cc) << 12);
        short8 Af[4][2], Bf[4][2];
        #pragma unroll
        for (int jt = 0; jt < 4; ++jt)
            #pragma unroll
            for (int kk = 0; kk < 2; ++kk)
                Af[jt][kk] = *reinterpret_cast<const short8*>(up + (16 * jt + lr) * 64 + kk * 32 + lh * 8);
        #pragma unroll
        for (int kt = 0; kt < 4; ++kt)
            #pragma unroll
            for (int kk = 0; kk < 2; ++kk)
                Bf[kt][kk] = *reinterpret_cast<const short8*>(
                    &sK2[cur][(16 * kt + lr) * 64 + (((kk * 4 + lh) ^ (lr & 7)) << 3)]);

        f32x4 zacc[4][4];
        #pragma unroll
        for (int jt = 0; jt < 4; ++jt)
            #pragma unroll
            for (int kt = 0; kt < 4; ++kt) zacc[jt][kt] = f32x4{0.f, 0.f, 0.f, 0.f};
        #pragma unroll
        for (int kk = 0; kk < 2; ++kk)
            #pragma unroll
            for (int jt = 0; jt < 4; ++jt)
                #pragma unroll
                for (int kt = 0; kt < 4; ++kt)
                    zacc[jt][kt] = __builtin_amdgcn_mfma_f32_16x16x32_bf16(
                        Af[jt][kk], Bf[kt][kk], zacc[jt][kt], 0, 0, 0);

        // ---- Z -> bf16 -> sZT[w] (transposed, swizzled) ----
        // lane holds Z[j = 16jt + 4lh + r][k = 16kt + lr]
        #pragma unroll
        for (int kt = 0; kt < 4; ++kt) {
            const int rbase = (16 * kt + lr) * 64;
            #pragma unroll
            for (int jt = 0; jt < 4; ++jt) {
                const f32x4 z = zacc[jt][kt];
                uint2 pk;
                pk.x = (unsigned)f2bf(z[0]) | ((unsigned)f2bf(z[1]) << 16);
                pk.y = (unsigned)f2bf(z[2]) | ((unsigned)f2bf(z[3]) << 16);
                const int g = (2 * jt + (lh >> 1)) ^ (lr & 7);
                *reinterpret_cast<uint2*>(&zt[rbase + (g << 3) + (lh & 1) * 4]) = pk;
            }
        }
        asm volatile("s_waitcnt lgkmcnt(0)" ::: "memory");
        __builtin_amdgcn_sched_barrier(0);

        // ---- mm2: out[i][k] += sum_j K1w[i][j] * Z[j][k] ----
        short8 A2[4][2], B2[4][2];
        #pragma unroll
        for (int it = 0; it < 4; ++it)
            #pragma unroll
            for (int jj = 0; jj < 2; ++jj)
                A2[it][jj] = *reinterpret_cast<const short8*>(
                    &sK1[cur][(16 * it + lr) * 64 + (((jj * 4 + lh) ^ (lr & 7)) << 3)]);
        #pragma unroll
        for (int kt = 0; kt < 4; ++kt)
            #pragma unroll
            for (int jj = 0; jj < 2; ++jj)
                B2[kt][jj] = *reinterpret_cast<const short8*>(
                    &zt[(16 * kt + lr) * 64 + (((jj * 4 + lh) ^ (lr & 7)) << 3)]);
        #pragma unroll
        for (int jj = 0; jj < 2; ++jj)
            #pragma unroll
            for (int it = 0; it < 4; ++it)
                #pragma unroll
                for (int kt = 0; kt < 4; ++kt)
                    oacc[it][kt] = __builtin_amdgcn_mfma_f32_16x16x32_bf16(
                        A2[it][jj], B2[kt][jj], oacc[it][kt], 0, 0, 0);

        __syncthreads();
    }
#undef STAGE

    // ---- partial store: part[ch][b][a][i][k] ----
    float* pp = part + ((((size_t)ch * B + b) * Q + a) << 12);
    #pragma unroll
    for (int it = 0; it < 4; ++it)
        #pragma unroll
        for (int kt = 0; kt < 4; ++kt)
            #pragma unroll
            for (int r = 0; r < 4; ++r)
                pp[(16 * it + 4 * lh + r) * 64 + 16 * kt + lr] = oacc[it][kt][r];
}

// ---------------------------------------------------------------------------
// Kernel 3: sum the 4 c-split partials into out.
// ---------------------------------------------------------------------------
__global__ __launch_bounds__(256)
void addparts_kernel(const float* __restrict__ part, float* __restrict__ out)
{
    const int g = blockIdx.x * 256 + threadIdx.x;     // float4 index
    constexpr size_t SLAB = (size_t)B * Q * NPTS / 4; // float4 per slab
    const float4* p = reinterpret_cast<const float4*>(part);
    float4 s0 = p[g];
    float4 s1 = p[g + SLAB];
    float4 s2 = p[g + 2 * SLAB];
    float4 s3 = p[g + 3 * SLAB];
    float4 r;
    r.x = (s0.x + s1.x) + (s2.x + s3.x);
    r.y = (s0.y + s1.y) + (s2.y + s3.y);
    r.z = (s0.z + s1.z) + (s2.z + s3.z);
    r.w = (s0.w + s1.w) + (s2.w + s3.w);
    reinterpret_cast<float4*>(out)[g] = r;
}

} // namespace

extern "C" void kernel_launch(void* const* d_in, const int* in_sizes, int n_in,
                              void* d_out, int out_size, void* d_ws, size_t ws_size,
                              hipStream_t stream)
{
    const float* u     = (const float*)d_in[0];
    const float* x1    = (const float*)d_in[1];
    const float* x2    = (const float*)d_in[2];
    const float* w1    = (const float*)d_in[3];
    const float* w2    = (const float*)d_in[4];
    const float* k1W0  = (const float*)d_in[5];
    const float* k1b0  = (const float*)d_in[6];
    const float* k1W1  = (const float*)d_in[7];
    const float* k1b1  = (const float*)d_in[8];
    const float* k1W2  = (const float*)d_in[9];
    const float* k1b2  = (const float*)d_in[10];
    const float* k2W0  = (const float*)d_in[11];
    const float* k2b0  = (const float*)d_in[12];
    const float* k2W1  = (const float*)d_in[13];
    const float* k2b1  = (const float*)d_in[14];
    const float* k2W2  = (const float*)d_in[15];
    const float* k2b2  = (const float*)d_in[16];

    float* out = (float*)d_out;
    char* ws = (char*)d_ws;
    size_t off = 0;
    ushort* K1buf = (ushort*)(ws + off); off += (size_t)QP * NPTS * 2;       // 8 MB
    ushort* K2buf = (ushort*)(ws + off); off += (size_t)QP * NPTS * 2;       // 8 MB
    ushort* W2Th  = (ushort*)(ws + off); off += 2 * 131072 * 2;
    ushort* W2Tl  = (ushort*)(ws + off); off += 2 * 131072 * 2;
    ushort* W1Th  = (ushort*)(ws + off); off += 2 * 16384 * 2;
    ushort* W1Tl  = (ushort*)(ws + off); off += 2 * 16384 * 2;
    ushort* ubf   = (ushort*)(ws + off); off += (size_t)B * P * NPTS * 2;    // 4 MB
    float*  part  = (float*)(ws + off);  off += (size_t)CH * B * Q * NPTS * 4; // 32 MB

    wsplit_kernel<<<dim3(1152), 256, 0, stream>>>(
        k1W1, k1W2, k2W1, k2W2, W1Th, W1Tl, W2Th, W2Tl);

    ucvt_kernel<<<dim3((B * P * NPTS) / (256 * 4)), 256, 0, stream>>>(u, ubf);

    mlp_kernel<<<dim3(64, 2, 2), 256, 0, stream>>>(
        x1, x2,
        k1W0, k1b0, k1b1, k1b2,
        k2W0, k2b0, k2b1, k2b2,
        W1Th, W1Tl, W2Th, W2Tl,
        w1, w2,
        K1buf, K2buf);

    contract_kernel<<<dim3(512), 256, 0, stream>>>(ubf, K1buf, K2buf, part);

    addparts_kernel<<<dim3((B * Q * NPTS) / (256 * 4)), 256, 0, stream>>>(part, out);
}